// Round 2
// baseline (90837.115 us; speedup 1.0000x reference)
//
#include <hip/hip_runtime.h>
#include <math.h>

#define L_   4
#define H_   8
#define D_   512
#define DH   64
#define DFF_ 2048
#define V_   8000
#define B_   16
#define SENC 128
#define T_   32
#define TP1  33
#define NEGV -1e9f
#define EPSV 1e-6f
#define SQRTD 22.627416997969522f   // sqrt(512)

// ---------------------------------------------------------------------------
// Generic fp32 GEMM: C[M,N] = A[M,K] @ W[K,N] (+bias) (+relu). Row-major.
// N % 64 == 0, K % 16 == 0 (true for all call sites). M arbitrary.
// ---------------------------------------------------------------------------
__global__ __launch_bounds__(256) void gemm_k(
    const float* __restrict__ A, const float* __restrict__ W,
    const float* __restrict__ bias, float* __restrict__ C,
    int M, int N, int K, int relu)
{
    __shared__ float As[16][64];
    __shared__ float Bs[16][64];
    int tid = threadIdx.x;
    int tx = tid & 15, ty = tid >> 4;
    int m0 = blockIdx.y * 64, n0 = blockIdx.x * 64;
    float acc[4][4] = {};
    for (int k0 = 0; k0 < K; k0 += 16) {
        #pragma unroll
        for (int i = 0; i < 4; i++) {           // A tile 64x16
            int idx = tid + i * 256;
            int m = idx >> 4, kk = idx & 15;
            int gm = m0 + m;
            As[kk][m] = (gm < M) ? A[(size_t)gm * K + k0 + kk] : 0.f;
        }
        #pragma unroll
        for (int i = 0; i < 4; i++) {           // W tile 16x64
            int idx = tid + i * 256;
            int kk = idx >> 6, n = idx & 63;
            Bs[kk][n] = W[(size_t)(k0 + kk) * N + n0 + n];
        }
        __syncthreads();
        #pragma unroll
        for (int kk = 0; kk < 16; kk++) {
            float a[4], b[4];
            #pragma unroll
            for (int i = 0; i < 4; i++) a[i] = As[kk][ty * 4 + i];
            #pragma unroll
            for (int j = 0; j < 4; j++) b[j] = Bs[kk][tx * 4 + j];
            #pragma unroll
            for (int i = 0; i < 4; i++)
                #pragma unroll
                for (int j = 0; j < 4; j++)
                    acc[i][j] += a[i] * b[j];
        }
        __syncthreads();
    }
    #pragma unroll
    for (int i = 0; i < 4; i++) {
        int gm = m0 + ty * 4 + i;
        if (gm >= M) continue;
        #pragma unroll
        for (int j = 0; j < 4; j++) {
            int gn = n0 + tx * 4 + j;
            float v = acc[i][j];
            if (bias) v += bias[gn];
            if (relu) v = fmaxf(v, 0.f);
            C[(size_t)gm * N + gn] = v;
        }
    }
}

// ---------------------------------------------------------------------------
// init: tokens[b][0]=START(1), rest NULL(0); done=0; cross mask = pm * NEG
// ---------------------------------------------------------------------------
__global__ void init_k(int* __restrict__ tokens, int* __restrict__ done,
                       float* __restrict__ cmask, const float* __restrict__ pm)
{
    int tid = threadIdx.x + blockIdx.x * 256;
    if (tid < B_ * TP1) tokens[tid] = ((tid % TP1) == 0) ? 1 : 0;
    if (tid < B_) done[tid] = 0;
    if (tid < B_ * SENC) cmask[tid] = pm[tid] * NEGV;
}

// ---------------------------------------------------------------------------
// x[p,b,:] = embed[tokens[b][p]] * sqrt(D) + pos_enc[p]   (position-major)
// ---------------------------------------------------------------------------
__global__ __launch_bounds__(256) void embed_k(
    const float* __restrict__ embed, const int* __restrict__ tokens,
    float* __restrict__ x)
{
    int p = blockIdx.x;
    int b = blockIdx.y;
    int tok = tokens[b * TP1 + p];
    const float* e = embed + (size_t)tok * D_;
    float* xr = x + ((size_t)p * B_ + b) * D_;
    for (int d = threadIdx.x; d < D_; d += 256) {
        float fd = (float)(2 * (d / 2)) / (float)D_;
        float ang = (float)p / powf(10000.f, fd);
        float pe = (d & 1) ? cosf(ang) : sinf(ang);
        xr[d] = e[d] * SQRTD + pe;
    }
}

// ---------------------------------------------------------------------------
// Self-attention: one 64-lane wave per (qpos, head, batch). P keys (all valid).
// ---------------------------------------------------------------------------
__global__ __launch_bounds__(64) void selfattn_k(
    const float* __restrict__ q, const float* __restrict__ k,
    const float* __restrict__ v, float* __restrict__ out, int P)
{
    int qp = blockIdx.x, h = blockIdx.y, b = blockIdx.z;
    int d = threadIdx.x;
    __shared__ float sc[TP1];
    float qd = q[((size_t)qp * B_ + b) * D_ + h * DH + d];
    for (int kp = 0; kp < P; kp++) {
        float s = qd * k[((size_t)kp * B_ + b) * D_ + h * DH + d];
        #pragma unroll
        for (int off = 32; off; off >>= 1) s += __shfl_xor(s, off);
        if (d == 0) sc[kp] = s * 0.125f;    // 1/sqrt(64)
    }
    __syncthreads();
    float mx = -1e30f;
    for (int kp = 0; kp < P; kp++) mx = fmaxf(mx, sc[kp]);
    float sum = 0.f, o = 0.f;
    for (int kp = 0; kp < P; kp++) {
        float w = expf(sc[kp] - mx);
        sum += w;
        o += w * v[((size_t)kp * B_ + b) * D_ + h * DH + d];
    }
    out[((size_t)qp * B_ + b) * D_ + h * DH + d] = o / sum;
}

// ---------------------------------------------------------------------------
// Cross-attention vs precomputed Kc/Vc ([b,s,d] for this layer), 128 keys.
// ---------------------------------------------------------------------------
__global__ __launch_bounds__(64) void crossattn_k(
    const float* __restrict__ q, const float* __restrict__ Kc,
    const float* __restrict__ Vc, const float* __restrict__ cmask,
    float* __restrict__ out)
{
    int qp = blockIdx.x, h = blockIdx.y, b = blockIdx.z;
    int d = threadIdx.x;
    __shared__ float sc[SENC];
    float qd = q[((size_t)qp * B_ + b) * D_ + h * DH + d];
    const float* kb = Kc + (size_t)b * SENC * D_ + h * DH + d;
    for (int s = 0; s < SENC; s++) {
        float t = qd * kb[(size_t)s * D_];
        #pragma unroll
        for (int off = 32; off; off >>= 1) t += __shfl_xor(t, off);
        if (d == 0) sc[s] = t * 0.125f + cmask[b * SENC + s];
    }
    __syncthreads();
    float mx = -1e30f;
    for (int s = 0; s < SENC; s++) mx = fmaxf(mx, sc[s]);
    float sum = 0.f, o = 0.f;
    const float* vb = Vc + (size_t)b * SENC * D_ + h * DH + d;
    for (int s = 0; s < SENC; s++) {
        float w = expf(sc[s] - mx);
        sum += w;
        o += w * vb[(size_t)s * D_];
    }
    out[((size_t)qp * B_ + b) * D_ + h * DH + d] = o / sum;
}

// ---------------------------------------------------------------------------
// x = LN(x + y) * g + b, one block per row (512 elems, 256 threads x 2)
// ---------------------------------------------------------------------------
__device__ __forceinline__ float block_sum(float s) {
    __shared__ float red[4];
    #pragma unroll
    for (int off = 32; off; off >>= 1) s += __shfl_xor(s, off);
    if ((threadIdx.x & 63) == 0) red[threadIdx.x >> 6] = s;
    __syncthreads();
    float tot = red[0] + red[1] + red[2] + red[3];
    __syncthreads();
    return tot;
}

__global__ __launch_bounds__(256) void ln_k(
    float* __restrict__ x, const float* __restrict__ y,
    const float* __restrict__ g, const float* __restrict__ bb)
{
    int r = blockIdx.x;
    float* xr = x + (size_t)r * D_;
    const float* yr = y + (size_t)r * D_;
    int tid = threadIdx.x;
    float v0 = xr[tid] + yr[tid];
    float v1 = xr[tid + 256] + yr[tid + 256];
    float mean = block_sum(v0 + v1) * (1.f / 512.f);
    float d0 = v0 - mean, d1 = v1 - mean;
    float var = block_sum(d0 * d0 + d1 * d1) * (1.f / 512.f);
    float rs = rsqrtf(var + EPSV);
    xr[tid]       = d0 * rs * g[tid]       + bb[tid];
    xr[tid + 256] = d1 * rs * g[tid + 256] + bb[tid + 256];
}

// ---------------------------------------------------------------------------
// logits[b][v] = x[t,b,:] . fc_w[:,v] + fc_b[v]; 16 batches per block,
// fc_w read exactly once per step across the grid.
// ---------------------------------------------------------------------------
__global__ __launch_bounds__(256) void logits_k(
    const float* __restrict__ x, const float* __restrict__ fcw,
    const float* __restrict__ fcb, float* __restrict__ logits, int t)
{
    __shared__ float xs[B_][D_];     // 32 KB
    int tid = threadIdx.x;
    for (int i = tid; i < B_ * D_; i += 256) {
        int b = i >> 9, d = i & 511;
        xs[b][d] = x[((size_t)t * B_ + b) * D_ + d];
    }
    __syncthreads();
    int v = blockIdx.x * 256 + tid;
    if (v >= V_) return;
    float acc[B_] = {};
    for (int k0 = 0; k0 < D_; k0++) {
        float w = fcw[(size_t)k0 * V_ + v];
        #pragma unroll
        for (int b = 0; b < B_; b++) acc[b] += xs[b][k0] * w;
    }
    float bias = fcb[v];
    #pragma unroll
    for (int b = 0; b < B_; b++) logits[(size_t)b * V_ + v] = acc[b] + bias;
}

// ---------------------------------------------------------------------------
// Per-batch argmax (first-index tie-break, matching jnp.argmax) + token update
// done |= (idx == END); tok = done ? NULL : idx; tokens[b][t+1] = tok
// ---------------------------------------------------------------------------
__global__ __launch_bounds__(256) void argmax_k(
    const float* __restrict__ logits, int* __restrict__ tokens,
    int* __restrict__ done, int t)
{
    int b = blockIdx.x;
    const float* lr = logits + (size_t)b * V_;
    float bv = -1e30f; int bi = 0x7fffffff;
    for (int v = threadIdx.x; v < V_; v += 256) {
        float val = lr[v];
        if (val > bv) { bv = val; bi = v; }
    }
    __shared__ float sv[256];
    __shared__ int si[256];
    sv[threadIdx.x] = bv; si[threadIdx.x] = bi;
    __syncthreads();
    for (int s = 128; s; s >>= 1) {
        if (threadIdx.x < s) {
            float ov = sv[threadIdx.x + s]; int oi = si[threadIdx.x + s];
            if (ov > sv[threadIdx.x] ||
                (ov == sv[threadIdx.x] && oi < si[threadIdx.x])) {
                sv[threadIdx.x] = ov; si[threadIdx.x] = oi;
            }
        }
        __syncthreads();
    }
    if (threadIdx.x == 0) {
        int idx = si[0];
        int dn = done[b] | (idx == 2 ? 1 : 0);
        done[b] = dn;
        tokens[b * TP1 + t + 1] = dn ? 0 : idx;
    }
}

// ---------------------------------------------------------------------------
// d_out[b*T + j] = tokens[b][j+1]  (int32 — harness reads int32 path)
// ---------------------------------------------------------------------------
__global__ void writeout_k(const int* __restrict__ tokens, int* __restrict__ out)
{
    int i = threadIdx.x + blockIdx.x * 256;
    if (i < B_ * T_) {
        int b = i / T_, j = i % T_;
        out[i] = tokens[b * TP1 + j + 1];
    }
}

// ---------------------------------------------------------------------------
extern "C" void kernel_launch(void* const* d_in, const int* in_sizes, int n_in,
                              void* d_out, int out_size, void* d_ws, size_t ws_size,
                              hipStream_t stream)
{
    const float* enc   = (const float*)d_in[1];   // [B,SENC,D]
    const float* pm    = (const float*)d_in[2];   // [B,SENC]
    const float* embed = (const float*)d_in[3];   // [V,D]
    const float* wq    = (const float*)d_in[4];
    const float* wk    = (const float*)d_in[5];
    const float* wv    = (const float*)d_in[6];
    const float* wo    = (const float*)d_in[7];
    const float* cwq   = (const float*)d_in[8];
    const float* cwk   = (const float*)d_in[9];
    const float* cwv   = (const float*)d_in[10];
    const float* cwo   = (const float*)d_in[11];
    const float* w1    = (const float*)d_in[12];  // [L,D,DFF]
    const float* b1    = (const float*)d_in[13];  // [L,DFF]
    const float* w2    = (const float*)d_in[14];  // [L,DFF,D]
    const float* b2    = (const float*)d_in[15];  // [L,D]
    const float* ln_g  = (const float*)d_in[16];  // [L,3,D]
    const float* ln_b  = (const float*)d_in[17];
    const float* fcw   = (const float*)d_in[18];  // [D,V]
    const float* fcb   = (const float*)d_in[19];  // [V]

    float* ws = (float*)d_ws;
    size_t off = 0;
    const size_t XSZ = (size_t)TP1 * B_ * D_;       // 270336
    float* x     = ws + off; off += XSZ;
    float* qb    = ws + off; off += XSZ;
    float* kb    = ws + off; off += XSZ;
    float* vb    = ws + off; off += XSZ;
    float* attn  = ws + off; off += XSZ;
    float* proj  = ws + off; off += XSZ;
    float* ffnh  = ws + off; off += (size_t)TP1 * B_ * DFF_;
    float* logits= ws + off; off += (size_t)B_ * V_;
    float* Kc    = ws + off; off += (size_t)L_ * B_ * SENC * D_;
    float* Vc    = ws + off; off += (size_t)L_ * B_ * SENC * D_;
    float* cmask = ws + off; off += (size_t)B_ * SENC;
    int* tokens  = (int*)(ws + off); off += (B_ * TP1 + 63) & ~63;
    int* done    = (int*)(ws + off); off += 64;

    init_k<<<8, 256, 0, stream>>>(tokens, done, cmask, pm);

    // Precompute cross K/V per layer: [B*SENC, D] @ [D, D]
    const size_t KVL = (size_t)B_ * SENC * D_;
    for (int l = 0; l < L_; l++) {
        gemm_k<<<dim3(D_ / 64, (B_ * SENC) / 64), 256, 0, stream>>>(
            enc, cwk + (size_t)l * D_ * D_, nullptr, Kc + l * KVL,
            B_ * SENC, D_, D_, 0);
        gemm_k<<<dim3(D_ / 64, (B_ * SENC) / 64), 256, 0, stream>>>(
            enc, cwv + (size_t)l * D_ * D_, nullptr, Vc + l * KVL,
            B_ * SENC, D_, D_, 0);
    }

    for (int t = 0; t < T_; t++) {
        int P = t + 1;
        int M = P * B_;
        dim3 g512(D_ / 64, (M + 63) / 64);
        dim3 gff(DFF_ / 64, (M + 63) / 64);
        dim3 gattn(P, H_, B_);

        embed_k<<<dim3(P, B_), 256, 0, stream>>>(embed, tokens, x);

        for (int l = 0; l < L_; l++) {
            const size_t lw = (size_t)l * D_ * D_;
            // --- self attention ---
            gemm_k<<<g512, 256, 0, stream>>>(x, wq + lw, nullptr, qb, M, D_, D_, 0);
            gemm_k<<<g512, 256, 0, stream>>>(x, wk + lw, nullptr, kb, M, D_, D_, 0);
            gemm_k<<<g512, 256, 0, stream>>>(x, wv + lw, nullptr, vb, M, D_, D_, 0);
            selfattn_k<<<gattn, 64, 0, stream>>>(qb, kb, vb, attn, P);
            gemm_k<<<g512, 256, 0, stream>>>(attn, wo + lw, nullptr, proj, M, D_, D_, 0);
            ln_k<<<M, 256, 0, stream>>>(x, proj, ln_g + (size_t)(l * 3 + 0) * D_,
                                        ln_b + (size_t)(l * 3 + 0) * D_);
            // --- cross attention ---
            gemm_k<<<g512, 256, 0, stream>>>(x, cwq + lw, nullptr, qb, M, D_, D_, 0);
            crossattn_k<<<gattn, 64, 0, stream>>>(qb, Kc + l * KVL, Vc + l * KVL,
                                                  cmask, attn);
            gemm_k<<<g512, 256, 0, stream>>>(attn, cwo + lw, nullptr, proj, M, D_, D_, 0);
            ln_k<<<M, 256, 0, stream>>>(x, proj, ln_g + (size_t)(l * 3 + 1) * D_,
                                        ln_b + (size_t)(l * 3 + 1) * D_);
            // --- FFN ---
            gemm_k<<<gff, 256, 0, stream>>>(x, w1 + (size_t)l * D_ * DFF_,
                                            b1 + (size_t)l * DFF_, ffnh, M, DFF_, D_, 1);
            gemm_k<<<g512, 256, 0, stream>>>(ffnh, w2 + (size_t)l * DFF_ * D_,
                                             b2 + (size_t)l * D_, proj, M, D_, DFF_, 0);
            ln_k<<<M, 256, 0, stream>>>(x, proj, ln_g + (size_t)(l * 3 + 2) * D_,
                                        ln_b + (size_t)(l * 3 + 2) * D_);
        }

        logits_k<<<(V_ + 255) / 256, 256, 0, stream>>>(x, fcw, fcb, logits, t);
        argmax_k<<<B_, 256, 0, stream>>>(logits, tokens, done, t);
    }

    writeout_k<<<2, 256, 0, stream>>>(tokens, (int*)d_out);
}

// Round 3
// 49992.896 us; speedup vs baseline: 1.8170x; 1.8170x over previous
//
#include <hip/hip_runtime.h>
#include <math.h>

#define L_   4
#define H_   8
#define D_   512
#define DH   64
#define DFF_ 2048
#define V_   8000
#define B_   16
#define SENC 128
#define T_   32
#define TP1  33
#define NEGV -1e9f
#define EPSV 1e-6f
#define SQRTD 22.627416997969522f   // sqrt(512)
#define XSZ  ((size_t)TP1 * B_ * D_)   // 270336 floats

// ---------------------------------------------------------------------------
// fp32 GEMM, 32x64 tile, 128 threads (4x4 micro-tile).
// C[M,N] = A[M,K(chunk)] @ W[K,N]; k-range = [blockIdx.z*kchunk, +kchunk);
// block z writes to C + z*pstride (split-K partials; pstride=0,gridz=1 normal).
// bias/relu only valid for non-split launches.
// ---------------------------------------------------------------------------
__global__ __launch_bounds__(128) void gemm32_k(
    const float* __restrict__ A, const float* __restrict__ W,
    const float* __restrict__ bias, float* __restrict__ C,
    int M, int N, int K, int kchunk, size_t pstride, int relu)
{
    __shared__ float As[16][32];
    __shared__ float Bs[16][64];
    int tid = threadIdx.x;
    int tx = tid & 15, ty = tid >> 4;          // tx 0..15, ty 0..7
    int m0 = blockIdx.y * 32, n0 = blockIdx.x * 64;
    int kbeg = blockIdx.z * kchunk, kend = kbeg + kchunk;
    C += (size_t)blockIdx.z * pstride;
    float acc[4][4] = {};
    for (int k0 = kbeg; k0 < kend; k0 += 16) {
        #pragma unroll
        for (int i = 0; i < 4; i++) {          // A tile 32x16 (512 elems)
            int idx = tid + i * 128;
            int m = idx >> 4, kk = idx & 15;
            int gm = m0 + m;
            As[kk][m] = (gm < M) ? A[(size_t)gm * K + k0 + kk] : 0.f;
        }
        #pragma unroll
        for (int i = 0; i < 8; i++) {          // W tile 16x64 (1024 elems)
            int idx = tid + i * 128;
            int kk = idx >> 6, n = idx & 63;
            Bs[kk][n] = W[(size_t)(k0 + kk) * N + n0 + n];
        }
        __syncthreads();
        #pragma unroll
        for (int kk = 0; kk < 16; kk++) {
            float a[4], b[4];
            #pragma unroll
            for (int i = 0; i < 4; i++) a[i] = As[kk][ty * 4 + i];
            #pragma unroll
            for (int j = 0; j < 4; j++) b[j] = Bs[kk][tx * 4 + j];
            #pragma unroll
            for (int i = 0; i < 4; i++)
                #pragma unroll
                for (int j = 0; j < 4; j++)
                    acc[i][j] += a[i] * b[j];
        }
        __syncthreads();
    }
    #pragma unroll
    for (int i = 0; i < 4; i++) {
        int gm = m0 + ty * 4 + i;
        if (gm >= M) continue;
        #pragma unroll
        for (int j = 0; j < 4; j++) {
            int gn = n0 + tx * 4 + j;
            float v = acc[i][j];
            if (bias) v += bias[gn];
            if (relu) v = fmaxf(v, 0.f);
            C[(size_t)gm * N + gn] = v;
        }
    }
}

// ---------------------------------------------------------------------------
// Fused QKV: blockIdx.x selects W in {wq,wk,wv} (x>>3) and n-tile (x&7).
// Output goes to qkv + sel*XSZ. M rows, N=K=512.
// ---------------------------------------------------------------------------
__global__ __launch_bounds__(128) void gemm_qkv_k(
    const float* __restrict__ A, const float* __restrict__ W0,
    const float* __restrict__ W1, const float* __restrict__ W2,
    float* __restrict__ Cb, int M)
{
    __shared__ float As[16][32];
    __shared__ float Bs[16][64];
    int sel = blockIdx.x >> 3;
    const float* W = (sel == 0) ? W0 : ((sel == 1) ? W1 : W2);
    float* C = Cb + (size_t)sel * XSZ;
    int tid = threadIdx.x;
    int tx = tid & 15, ty = tid >> 4;
    int m0 = blockIdx.y * 32, n0 = (blockIdx.x & 7) * 64;
    float acc[4][4] = {};
    for (int k0 = 0; k0 < D_; k0 += 16) {
        #pragma unroll
        for (int i = 0; i < 4; i++) {
            int idx = tid + i * 128;
            int m = idx >> 4, kk = idx & 15;
            int gm = m0 + m;
            As[kk][m] = (gm < M) ? A[(size_t)gm * D_ + k0 + kk] : 0.f;
        }
        #pragma unroll
        for (int i = 0; i < 8; i++) {
            int idx = tid + i * 128;
            int kk = idx >> 6, n = idx & 63;
            Bs[kk][n] = W[(size_t)(k0 + kk) * D_ + n0 + n];
        }
        __syncthreads();
        #pragma unroll
        for (int kk = 0; kk < 16; kk++) {
            float a[4], b[4];
            #pragma unroll
            for (int i = 0; i < 4; i++) a[i] = As[kk][ty * 4 + i];
            #pragma unroll
            for (int j = 0; j < 4; j++) b[j] = Bs[kk][tx * 4 + j];
            #pragma unroll
            for (int i = 0; i < 4; i++)
                #pragma unroll
                for (int j = 0; j < 4; j++)
                    acc[i][j] += a[i] * b[j];
        }
        __syncthreads();
    }
    #pragma unroll
    for (int i = 0; i < 4; i++) {
        int gm = m0 + ty * 4 + i;
        if (gm >= M) continue;
        #pragma unroll
        for (int j = 0; j < 4; j++)
            C[(size_t)gm * D_ + n0 + tx * 4 + j] = acc[i][j];
    }
}

// ---------------------------------------------------------------------------
// init: tokens[b][0]=START(1), rest NULL(0); done=0; cross mask = pm * NEG
// ---------------------------------------------------------------------------
__global__ void init_k(int* __restrict__ tokens, int* __restrict__ done,
                       float* __restrict__ cmask, const float* __restrict__ pm)
{
    int tid = threadIdx.x + blockIdx.x * 256;
    if (tid < B_ * TP1) tokens[tid] = ((tid % TP1) == 0) ? 1 : 0;
    if (tid < B_) done[tid] = 0;
    if (tid < B_ * SENC) cmask[tid] = pm[tid] * NEGV;
}

// ---------------------------------------------------------------------------
// x[p,b,:] = embed[tokens[b][p]] * sqrt(D) + pos_enc[p]   (position-major)
// ---------------------------------------------------------------------------
__global__ __launch_bounds__(256) void embed_k(
    const float* __restrict__ embed, const int* __restrict__ tokens,
    float* __restrict__ x)
{
    int p = blockIdx.x;
    int b = blockIdx.y;
    int tok = tokens[b * TP1 + p];
    const float* e = embed + (size_t)tok * D_;
    float* xr = x + ((size_t)p * B_ + b) * D_;
    for (int d = threadIdx.x; d < D_; d += 256) {
        float fd = (float)(2 * (d / 2)) / (float)D_;
        float ang = (float)p / powf(10000.f, fd);
        float pe = (d & 1) ? cosf(ang) : sinf(ang);
        xr[d] = e[d] * SQRTD + pe;
    }
}

// ---------------------------------------------------------------------------
// Self-attention: one 64-lane wave per (qpos, head, batch). P keys.
// ---------------------------------------------------------------------------
__global__ __launch_bounds__(64) void selfattn_k(
    const float* __restrict__ q, const float* __restrict__ k,
    const float* __restrict__ v, float* __restrict__ out, int P)
{
    int qp = blockIdx.x, h = blockIdx.y, b = blockIdx.z;
    int d = threadIdx.x;
    __shared__ float sc[TP1];
    float qd = q[((size_t)qp * B_ + b) * D_ + h * DH + d];
    for (int kp = 0; kp < P; kp++) {
        float s = qd * k[((size_t)kp * B_ + b) * D_ + h * DH + d];
        #pragma unroll
        for (int off = 32; off; off >>= 1) s += __shfl_xor(s, off);
        if (d == 0) sc[kp] = s * 0.125f;    // 1/sqrt(64)
    }
    __syncthreads();
    float mx = -1e30f;
    for (int kp = 0; kp < P; kp++) mx = fmaxf(mx, sc[kp]);
    float sum = 0.f, o = 0.f;
    for (int kp = 0; kp < P; kp++) {
        float w = expf(sc[kp] - mx);
        sum += w;
        o += w * v[((size_t)kp * B_ + b) * D_ + h * DH + d];
    }
    out[((size_t)qp * B_ + b) * D_ + h * DH + d] = o / sum;
}

// ---------------------------------------------------------------------------
// Cross-attention vs precomputed Kc/Vc ([b,s,d] for this layer), 128 keys.
// ---------------------------------------------------------------------------
__global__ __launch_bounds__(64) void crossattn_k(
    const float* __restrict__ q, const float* __restrict__ Kc,
    const float* __restrict__ Vc, const float* __restrict__ cmask,
    float* __restrict__ out)
{
    int qp = blockIdx.x, h = blockIdx.y, b = blockIdx.z;
    int d = threadIdx.x;
    __shared__ float sc[SENC];
    float qd = q[((size_t)qp * B_ + b) * D_ + h * DH + d];
    const float* kb = Kc + (size_t)b * SENC * D_ + h * DH + d;
    for (int s = 0; s < SENC; s++) {
        float t = qd * kb[(size_t)s * D_];
        #pragma unroll
        for (int off = 32; off; off >>= 1) t += __shfl_xor(t, off);
        if (d == 0) sc[s] = t * 0.125f + cmask[b * SENC + s];
    }
    __syncthreads();
    float mx = -1e30f;
    for (int s = 0; s < SENC; s++) mx = fmaxf(mx, sc[s]);
    float sum = 0.f, o = 0.f;
    const float* vb = Vc + (size_t)b * SENC * D_ + h * DH + d;
    for (int s = 0; s < SENC; s++) {
        float w = expf(sc[s] - mx);
        sum += w;
        o += w * vb[(size_t)s * D_];
    }
    out[((size_t)qp * B_ + b) * D_ + h * DH + d] = o / sum;
}

// ---------------------------------------------------------------------------
// x = LN(x + sum_parts (+ bias)) * g + b. One block per row.
// parts: nparts partial buffers at stride pstride (split-K reduction fused).
// ---------------------------------------------------------------------------
__device__ __forceinline__ float block_sum(float s) {
    __shared__ float red[4];
    #pragma unroll
    for (int off = 32; off; off >>= 1) s += __shfl_xor(s, off);
    if ((threadIdx.x & 63) == 0) red[threadIdx.x >> 6] = s;
    __syncthreads();
    float tot = red[0] + red[1] + red[2] + red[3];
    __syncthreads();
    return tot;
}

__global__ __launch_bounds__(256) void ln_red_k(
    float* __restrict__ x, const float* __restrict__ parts, size_t pstride,
    int nparts, const float* __restrict__ bias,
    const float* __restrict__ gam, const float* __restrict__ bet)
{
    int r = blockIdx.x;
    float* xr = x + (size_t)r * D_;
    int tid = threadIdx.x;
    float v0 = xr[tid];
    float v1 = xr[tid + 256];
    for (int s = 0; s < nparts; s++) {
        const float* pr = parts + (size_t)s * pstride + (size_t)r * D_;
        v0 += pr[tid];
        v1 += pr[tid + 256];
    }
    if (bias) { v0 += bias[tid]; v1 += bias[tid + 256]; }
    float mean = block_sum(v0 + v1) * (1.f / 512.f);
    float d0 = v0 - mean, d1 = v1 - mean;
    float var = block_sum(d0 * d0 + d1 * d1) * (1.f / 512.f);
    float rs = rsqrtf(var + EPSV);
    xr[tid]       = d0 * rs * gam[tid]       + bet[tid];
    xr[tid + 256] = d1 * rs * gam[tid + 256] + bet[tid + 256];
}

// ---------------------------------------------------------------------------
// logits[b][v] for 16 batches. Grid 125 blocks x 64 vocab; 256 threads =
// 64 cols x 4 K-chunks of 128 (in-block split-K, LDS reduce).
// ---------------------------------------------------------------------------
__global__ __launch_bounds__(256) void logits_k(
    const float* __restrict__ x, const float* __restrict__ fcw,
    const float* __restrict__ fcb, float* __restrict__ logits, int t)
{
    __shared__ float xs[B_][D_];                 // 32 KB
    __shared__ float red[4][64][B_];             // 16 KB
    int tid = threadIdx.x;
    for (int i = tid; i < B_ * D_; i += 256) {
        int b = i >> 9, d = i & 511;
        xs[b][d] = x[((size_t)t * B_ + b) * D_ + d];
    }
    __syncthreads();
    int lane = tid & 63, ks = tid >> 6;
    int col = blockIdx.x * 64 + lane;
    float acc[B_] = {};
    int kb = ks * 128;
    for (int k = kb; k < kb + 128; k++) {
        float w = fcw[(size_t)k * V_ + col];
        #pragma unroll
        for (int b = 0; b < B_; b++) acc[b] += xs[b][k] * w;
    }
    #pragma unroll
    for (int b = 0; b < B_; b++) red[ks][lane][b] = acc[b];
    __syncthreads();
    if (ks == 0) {
        float bias = fcb[col];
        #pragma unroll
        for (int b = 0; b < B_; b++) {
            float s = red[0][lane][b] + red[1][lane][b]
                    + red[2][lane][b] + red[3][lane][b];
            logits[(size_t)b * V_ + col] = s + bias;
        }
    }
}

// ---------------------------------------------------------------------------
// Per-batch argmax (first-index tie-break) + token update
// ---------------------------------------------------------------------------
__global__ __launch_bounds__(256) void argmax_k(
    const float* __restrict__ logits, int* __restrict__ tokens,
    int* __restrict__ done, int t)
{
    int b = blockIdx.x;
    const float* lr = logits + (size_t)b * V_;
    float bv = -1e30f; int bi = 0x7fffffff;
    for (int v = threadIdx.x; v < V_; v += 256) {
        float val = lr[v];
        if (val > bv) { bv = val; bi = v; }
    }
    __shared__ float sv[256];
    __shared__ int si[256];
    sv[threadIdx.x] = bv; si[threadIdx.x] = bi;
    __syncthreads();
    for (int s = 128; s; s >>= 1) {
        if (threadIdx.x < s) {
            float ov = sv[threadIdx.x + s]; int oi = si[threadIdx.x + s];
            if (ov > sv[threadIdx.x] ||
                (ov == sv[threadIdx.x] && oi < si[threadIdx.x])) {
                sv[threadIdx.x] = ov; si[threadIdx.x] = oi;
            }
        }
        __syncthreads();
    }
    if (threadIdx.x == 0) {
        int idx = si[0];
        int dn = done[b] | (idx == 2 ? 1 : 0);
        done[b] = dn;
        tokens[b * TP1 + t + 1] = dn ? 0 : idx;
    }
}

// ---------------------------------------------------------------------------
__global__ void writeout_k(const int* __restrict__ tokens, int* __restrict__ out)
{
    int i = threadIdx.x + blockIdx.x * 256;
    if (i < B_ * T_) {
        int b = i / T_, j = i % T_;
        out[i] = tokens[b * TP1 + j + 1];
    }
}

// ---------------------------------------------------------------------------
extern "C" void kernel_launch(void* const* d_in, const int* in_sizes, int n_in,
                              void* d_out, int out_size, void* d_ws, size_t ws_size,
                              hipStream_t stream)
{
    const float* enc   = (const float*)d_in[1];   // [B,SENC,D]
    const float* pm    = (const float*)d_in[2];   // [B,SENC]
    const float* embed = (const float*)d_in[3];   // [V,D]
    const float* wq    = (const float*)d_in[4];
    const float* wk    = (const float*)d_in[5];
    const float* wv    = (const float*)d_in[6];
    const float* wo    = (const float*)d_in[7];
    const float* cwq   = (const float*)d_in[8];
    const float* cwk   = (const float*)d_in[9];
    const float* cwv   = (const float*)d_in[10];
    const float* cwo   = (const float*)d_in[11];
    const float* w1    = (const float*)d_in[12];  // [L,D,DFF]
    const float* b1    = (const float*)d_in[13];  // [L,DFF]
    const float* w2    = (const float*)d_in[14];  // [L,DFF,D]
    const float* b2    = (const float*)d_in[15];  // [L,D]
    const float* ln_g  = (const float*)d_in[16];  // [L,3,D]
    const float* ln_b  = (const float*)d_in[17];
    const float* fcw   = (const float*)d_in[18];  // [D,V]
    const float* fcb   = (const float*)d_in[19];  // [V]

    float* ws = (float*)d_ws;
    size_t off = 0;
    float* x     = ws + off; off += XSZ;
    float* qkv   = ws + off; off += 3 * XSZ;      // q | k | v  (contiguous)
    float* attn  = ws + off; off += XSZ;
    float* parts = ws + off; off += 4 * XSZ;      // split-K partials
    float* ffnh  = ws + off; off += (size_t)TP1 * B_ * DFF_;
    float* logits= ws + off; off += (size_t)B_ * V_;
    float* Kc    = ws + off; off += (size_t)L_ * B_ * SENC * D_;
    float* Vc    = ws + off; off += (size_t)L_ * B_ * SENC * D_;
    float* cmask = ws + off; off += (size_t)B_ * SENC;
    int* tokens  = (int*)(ws + off); off += (B_ * TP1 + 63) & ~63;
    int* done    = (int*)(ws + off); off += 64;

    init_k<<<8, 256, 0, stream>>>(tokens, done, cmask, pm);

    // Precompute cross K/V per layer: [B*SENC, D] @ [D, D]
    const size_t KVL = (size_t)B_ * SENC * D_;
    for (int l = 0; l < L_; l++) {
        gemm32_k<<<dim3(8, (B_ * SENC) / 32), 128, 0, stream>>>(
            enc, cwk + (size_t)l * D_ * D_, nullptr, Kc + l * KVL,
            B_ * SENC, D_, D_, D_, 0, 0);
        gemm32_k<<<dim3(8, (B_ * SENC) / 32), 128, 0, stream>>>(
            enc, cwv + (size_t)l * D_ * D_, nullptr, Vc + l * KVL,
            B_ * SENC, D_, D_, D_, 0, 0);
    }

    for (int t = 0; t < T_; t++) {
        int P = t + 1;
        int M = P * B_;
        int mt = (M + 31) / 32;
        dim3 gattn(P, H_, B_);

        embed_k<<<dim3(P, B_), 256, 0, stream>>>(embed, tokens, x);

        for (int l = 0; l < L_; l++) {
            const size_t lw = (size_t)l * D_ * D_;
            // --- self attention ---
            gemm_qkv_k<<<dim3(24, mt), 128, 0, stream>>>(
                x, wq + lw, wk + lw, wv + lw, qkv, M);
            selfattn_k<<<gattn, 64, 0, stream>>>(qkv, qkv + XSZ, qkv + 2 * XSZ,
                                                 attn, P);
            gemm32_k<<<dim3(8, mt, 2), 128, 0, stream>>>(     // wo, split-K 2
                attn, wo + lw, nullptr, parts, M, D_, D_, 256, XSZ, 0);
            ln_red_k<<<M, 256, 0, stream>>>(x, parts, XSZ, 2, nullptr,
                ln_g + (size_t)(l * 3 + 0) * D_, ln_b + (size_t)(l * 3 + 0) * D_);
            // --- cross attention ---
            gemm32_k<<<dim3(8, mt), 128, 0, stream>>>(
                x, cwq + lw, nullptr, qkv, M, D_, D_, D_, 0, 0);
            crossattn_k<<<gattn, 64, 0, stream>>>(qkv, Kc + l * KVL, Vc + l * KVL,
                                                  cmask, attn);
            gemm32_k<<<dim3(8, mt, 2), 128, 0, stream>>>(     // cwo, split-K 2
                attn, cwo + lw, nullptr, parts, M, D_, D_, 256, XSZ, 0);
            ln_red_k<<<M, 256, 0, stream>>>(x, parts, XSZ, 2, nullptr,
                ln_g + (size_t)(l * 3 + 1) * D_, ln_b + (size_t)(l * 3 + 1) * D_);
            // --- FFN ---
            gemm32_k<<<dim3(32, mt), 128, 0, stream>>>(       // w1 + bias + relu
                x, w1 + (size_t)l * D_ * DFF_, b1 + (size_t)l * DFF_, ffnh,
                M, DFF_, D_, D_, 0, 1);
            gemm32_k<<<dim3(8, mt, 4), 128, 0, stream>>>(     // w2, split-K 4
                ffnh, w2 + (size_t)l * DFF_ * D_, nullptr, parts,
                M, D_, DFF_, 512, XSZ, 0);
            ln_red_k<<<M, 256, 0, stream>>>(x, parts, XSZ, 4, b2 + (size_t)l * D_,
                ln_g + (size_t)(l * 3 + 2) * D_, ln_b + (size_t)(l * 3 + 2) * D_);
        }

        logits_k<<<V_ / 64, 256, 0, stream>>>(x, fcw, fcb, logits, t);
        argmax_k<<<B_, 256, 0, stream>>>(logits, tokens, done, t);
    }

    writeout_k<<<2, 256, 0, stream>>>(tokens, (int*)d_out);
}

// Round 4
// 27112.494 us; speedup vs baseline: 3.3504x; 1.8439x over previous
//
#include <hip/hip_runtime.h>
#include <math.h>

#define L_   4
#define H_   8
#define D_   512
#define DH   64
#define DFF_ 2048
#define V_   8000
#define B_   16
#define SENC 128
#define T_   32
#define TP1  33
#define NEGV -1e9f
#define EPSV 1e-6f
#define SQRTD 22.627416997969522f   // sqrt(512)
#define XSZ  ((size_t)TP1 * B_ * D_)   // 270336 floats

// ---------------------------------------------------------------------------
// fp32 GEMM, 32x64 tile, 128 threads (4x4 micro-tile), float4 LDS paths.
// k-range = [blockIdx.z*kchunk, +kchunk); block z writes C + z*pstride.
// tmode==1: Kc-transpose epilogue (write KcT[((b*8+h)*64+d)*128+s],
//           gm=(b<<7)|s, gn=h*64+d).
// ---------------------------------------------------------------------------
__global__ __launch_bounds__(128) void gemm32_k(
    const float* __restrict__ A, const float* __restrict__ W,
    const float* __restrict__ bias, float* __restrict__ C,
    int M, int N, int K, int kchunk, size_t pstride, int relu, int tmode)
{
    __shared__ __align__(16) float As[16][32];
    __shared__ __align__(16) float Bs[16][64];
    int tid = threadIdx.x;
    int tx = tid & 15, ty = tid >> 4;
    int m0 = blockIdx.y * 32, n0 = blockIdx.x * 64;
    int kbeg = blockIdx.z * kchunk, kend = kbeg + kchunk;
    C += (size_t)blockIdx.z * pstride;
    int am = tid >> 2, aseg = tid & 3;        // A loader: row, k-quad
    int bk = tid >> 4, bc4 = (tid & 15) * 4;  // B loader: k-row, 4-col
    float acc[4][4] = {};
    for (int k0 = kbeg; k0 < kend; k0 += 16) {
        int gm = m0 + am;
        float4 av = make_float4(0.f, 0.f, 0.f, 0.f);
        if (gm < M) av = *(const float4*)&A[(size_t)gm * K + k0 + aseg * 4];
        As[aseg * 4 + 0][am] = av.x;
        As[aseg * 4 + 1][am] = av.y;
        As[aseg * 4 + 2][am] = av.z;
        As[aseg * 4 + 3][am] = av.w;
        *(float4*)&Bs[bk][bc4] =
            *(const float4*)&W[(size_t)(k0 + bk) * N + n0 + bc4];
        *(float4*)&Bs[bk + 8][bc4] =
            *(const float4*)&W[(size_t)(k0 + bk + 8) * N + n0 + bc4];
        __syncthreads();
        #pragma unroll
        for (int kk = 0; kk < 16; kk++) {
            float4 a4 = *(const float4*)&As[kk][ty * 4];
            float4 b4 = *(const float4*)&Bs[kk][tx * 4];
            float a[4] = {a4.x, a4.y, a4.z, a4.w};
            float b[4] = {b4.x, b4.y, b4.z, b4.w};
            #pragma unroll
            for (int i = 0; i < 4; i++)
                #pragma unroll
                for (int j = 0; j < 4; j++)
                    acc[i][j] += a[i] * b[j];
        }
        __syncthreads();
    }
    #pragma unroll
    for (int i = 0; i < 4; i++) {
        int gm = m0 + ty * 4 + i;
        if (gm >= M) continue;
        #pragma unroll
        for (int j = 0; j < 4; j++) {
            int gn = n0 + tx * 4 + j;
            float v = acc[i][j];
            if (bias) v += bias[gn];
            if (relu) v = fmaxf(v, 0.f);
            if (tmode == 1)
                C[(size_t)(gm >> 7) * 65536 + (size_t)gn * SENC + (gm & 127)] = v;
            else
                C[(size_t)gm * N + gn] = v;
        }
    }
}

// ---------------------------------------------------------------------------
// Fused QKV: blockIdx.x: sel = x>>3 in {q,k,v}, n-tile = x&7. N=K=512.
// q,v written row-major; k written TRANSPOSED: kT[((b*8+h)*64+d)*33 + p],
// gm = p*16+b, gn = h*64+d  ->  off = (gm&15)*16896 + gn*33 + (gm>>4).
// ---------------------------------------------------------------------------
__global__ __launch_bounds__(128) void gemm_qkv_k(
    const float* __restrict__ A, const float* __restrict__ W0,
    const float* __restrict__ W1, const float* __restrict__ W2,
    float* __restrict__ Cb, int M)
{
    __shared__ __align__(16) float As[16][32];
    __shared__ __align__(16) float Bs[16][64];
    int sel = blockIdx.x >> 3;
    const float* W = (sel == 0) ? W0 : ((sel == 1) ? W1 : W2);
    float* C = Cb + (size_t)sel * XSZ;
    int tid = threadIdx.x;
    int tx = tid & 15, ty = tid >> 4;
    int m0 = blockIdx.y * 32, n0 = (blockIdx.x & 7) * 64;
    int am = tid >> 2, aseg = tid & 3;
    int bk = tid >> 4, bc4 = (tid & 15) * 4;
    float acc[4][4] = {};
    for (int k0 = 0; k0 < D_; k0 += 16) {
        int gm = m0 + am;
        float4 av = make_float4(0.f, 0.f, 0.f, 0.f);
        if (gm < M) av = *(const float4*)&A[(size_t)gm * D_ + k0 + aseg * 4];
        As[aseg * 4 + 0][am] = av.x;
        As[aseg * 4 + 1][am] = av.y;
        As[aseg * 4 + 2][am] = av.z;
        As[aseg * 4 + 3][am] = av.w;
        *(float4*)&Bs[bk][bc4] =
            *(const float4*)&W[(size_t)(k0 + bk) * D_ + n0 + bc4];
        *(float4*)&Bs[bk + 8][bc4] =
            *(const float4*)&W[(size_t)(k0 + bk + 8) * D_ + n0 + bc4];
        __syncthreads();
        #pragma unroll
        for (int kk = 0; kk < 16; kk++) {
            float4 a4 = *(const float4*)&As[kk][ty * 4];
            float4 b4 = *(const float4*)&Bs[kk][tx * 4];
            float a[4] = {a4.x, a4.y, a4.z, a4.w};
            float b[4] = {b4.x, b4.y, b4.z, b4.w};
            #pragma unroll
            for (int i = 0; i < 4; i++)
                #pragma unroll
                for (int j = 0; j < 4; j++)
                    acc[i][j] += a[i] * b[j];
        }
        __syncthreads();
    }
    #pragma unroll
    for (int i = 0; i < 4; i++) {
        int gm = m0 + ty * 4 + i;
        if (gm >= M) continue;
        #pragma unroll
        for (int j = 0; j < 4; j++) {
            int gn = n0 + tx * 4 + j;
            if (sel == 1)
                C[(size_t)(gm & 15) * 16896 + (size_t)gn * TP1 + (gm >> 4)] =
                    acc[i][j];
            else
                C[(size_t)gm * D_ + gn] = acc[i][j];
        }
    }
}

// ---------------------------------------------------------------------------
__global__ void init_k(int* __restrict__ tokens, int* __restrict__ done,
                       float* __restrict__ cmask, const float* __restrict__ pm)
{
    int tid = threadIdx.x + blockIdx.x * 256;
    if (tid < B_ * TP1) tokens[tid] = ((tid % TP1) == 0) ? 1 : 0;
    if (tid < B_) done[tid] = 0;
    if (tid < B_ * SENC) cmask[tid] = pm[tid] * NEGV;
}

// ---------------------------------------------------------------------------
// x[p,b,:] = embed[tokens[b][p]] * sqrt(D) + pos_enc[p]
// ---------------------------------------------------------------------------
__global__ __launch_bounds__(256) void embed_k(
    const float* __restrict__ embed, const int* __restrict__ tokens,
    float* __restrict__ x)
{
    int p = blockIdx.x;
    int b = blockIdx.y;
    int tok = tokens[b * TP1 + p];
    const float* e = embed + (size_t)tok * D_;
    float* xr = x + ((size_t)p * B_ + b) * D_;
    for (int d = threadIdx.x; d < D_; d += 256) {
        float fd = (float)(2 * (d / 2)) / (float)D_;
        float ang = (float)p / powf(10000.f, fd);
        float pe = (d & 1) ? cosf(ang) : sinf(ang);
        xr[d] = e[d] * SQRTD + pe;
    }
}

// ---------------------------------------------------------------------------
__device__ __forceinline__ float block_sum(float s) {
    __shared__ float red[4];
    #pragma unroll
    for (int off = 32; off; off >>= 1) s += __shfl_xor(s, off);
    if ((threadIdx.x & 63) == 0) red[threadIdx.x >> 6] = s;
    __syncthreads();
    float tot = red[0] + red[1] + red[2] + red[3];
    __syncthreads();
    return tot;
}

// ---------------------------------------------------------------------------
// Fused self-attn + out-proj + residual + LN. One block per row r = p*16+b.
// q row-major, kT transposed [(b*8+h)*64+d][33], v row-major.
// ---------------------------------------------------------------------------
__global__ __launch_bounds__(256) void self_fused_k(
    const float* __restrict__ q, const float* __restrict__ kT,
    const float* __restrict__ v, const float* __restrict__ wo,
    float* __restrict__ x, const float* __restrict__ gam,
    const float* __restrict__ bet, int P)
{
    int r = blockIdx.x;
    int b = r & 15;
    int tid = threadIdx.x;
    __shared__ float qrow[D_], attnrow[D_];
    __shared__ float scs[H_][32];
    __shared__ float inv[H_];
    qrow[tid]       = q[(size_t)r * D_ + tid];
    qrow[tid + 256] = q[(size_t)r * D_ + tid + 256];
    __syncthreads();
    // scores: thread (h = tid>>5, kp = tid&31)
    {
        int kp = tid & 31, h = tid >> 5;
        float acc = 0.f;
        if (kp < P) {
            const float* kb = kT + ((size_t)(b * 8 + h) * 64) * TP1 + kp;
            for (int d = 0; d < 64; d++)
                acc += qrow[h * 64 + d] * kb[(size_t)d * TP1];
        }
        scs[h][kp] = acc * 0.125f;
    }
    __syncthreads();
    if (tid < 8) {   // per-head softmax
        float mx = -1e30f;
        for (int j = 0; j < P; j++) mx = fmaxf(mx, scs[tid][j]);
        float sum = 0.f;
        for (int j = 0; j < P; j++) {
            float e = expf(scs[tid][j] - mx);
            scs[tid][j] = e;
            sum += e;
        }
        inv[tid] = 1.f / sum;
    }
    __syncthreads();
    // weighted V: thread covers cols tid and tid+256
    {
        int h0 = tid >> 6, h1 = h0 + 4;
        float o0 = 0.f, o1 = 0.f;
        for (int j = 0; j < P; j++) {
            const float* vr = v + ((size_t)j * B_ + b) * D_;
            o0 += scs[h0][j] * vr[tid];
            o1 += scs[h1][j] * vr[tid + 256];
        }
        attnrow[tid]       = o0 * inv[h0];
        attnrow[tid + 256] = o1 * inv[h1];
    }
    __syncthreads();
    // out-proj + residual + LN
    float v0 = x[(size_t)r * D_ + tid];
    float v1 = x[(size_t)r * D_ + tid + 256];
    for (int k0 = 0; k0 < D_; k0++) {
        float a = attnrow[k0];
        v0 += a * wo[(size_t)k0 * D_ + tid];
        v1 += a * wo[(size_t)k0 * D_ + tid + 256];
    }
    float mean = block_sum(v0 + v1) * (1.f / 512.f);
    float d0 = v0 - mean, d1 = v1 - mean;
    float var = block_sum(d0 * d0 + d1 * d1) * (1.f / 512.f);
    float rs = rsqrtf(var + EPSV);
    x[(size_t)r * D_ + tid]       = d0 * rs * gam[tid] + bet[tid];
    x[(size_t)r * D_ + tid + 256] = d1 * rs * gam[tid + 256] + bet[tid + 256];
}

// ---------------------------------------------------------------------------
// Fused cross block: q-proj + attn(128 enc keys) + out-proj + residual + LN.
// KcT layout [(b*8+h)*64+d][128]; Vc row-major [(b*128+s)][512].
// ---------------------------------------------------------------------------
__global__ __launch_bounds__(256) void cross_fused_k(
    const float* __restrict__ KcT, const float* __restrict__ Vc,
    const float* __restrict__ cmask, const float* __restrict__ cwq,
    const float* __restrict__ cwo, float* __restrict__ x,
    const float* __restrict__ gam, const float* __restrict__ bet)
{
    int r = blockIdx.x;
    int b = r & 15;
    int tid = threadIdx.x;
    __shared__ float xs[D_], qrow[D_], attnrow[D_];
    __shared__ float scs[H_][SENC];
    __shared__ float inv[H_];
    xs[tid]       = x[(size_t)r * D_ + tid];
    xs[tid + 256] = x[(size_t)r * D_ + tid + 256];
    __syncthreads();
    // q projection
    {
        float q0 = 0.f, q1 = 0.f;
        for (int k0 = 0; k0 < D_; k0++) {
            float a = xs[k0];
            q0 += a * cwq[(size_t)k0 * D_ + tid];
            q1 += a * cwq[(size_t)k0 * D_ + tid + 256];
        }
        qrow[tid] = q0;
        qrow[tid + 256] = q1;
    }
    __syncthreads();
    // scores: 4 (h,s) pairs per thread
    #pragma unroll
    for (int j = 0; j < 4; j++) {
        int idx = tid + j * 256;
        int h = idx >> 7, s = idx & 127;
        const float* kb = KcT + ((size_t)(b * 512 + h * 64)) * SENC + s;
        float acc = 0.f;
        for (int d = 0; d < 64; d++)
            acc += qrow[h * 64 + d] * kb[(size_t)d * SENC];
        scs[h][s] = acc * 0.125f + cmask[b * SENC + s];
    }
    __syncthreads();
    if (tid < 8) {
        float mx = -1e30f;
        for (int s = 0; s < SENC; s++) mx = fmaxf(mx, scs[tid][s]);
        float sum = 0.f;
        for (int s = 0; s < SENC; s++) {
            float e = expf(scs[tid][s] - mx);
            scs[tid][s] = e;
            sum += e;
        }
        inv[tid] = 1.f / sum;
    }
    __syncthreads();
    {
        int h0 = tid >> 6, h1 = h0 + 4;
        float o0 = 0.f, o1 = 0.f;
        for (int s = 0; s < SENC; s++) {
            const float* vr = Vc + ((size_t)b * SENC + s) * D_;
            o0 += scs[h0][s] * vr[tid];
            o1 += scs[h1][s] * vr[tid + 256];
        }
        attnrow[tid]       = o0 * inv[h0];
        attnrow[tid + 256] = o1 * inv[h1];
    }
    __syncthreads();
    // out-proj + residual + LN
    float v0 = xs[tid];
    float v1 = xs[tid + 256];
    for (int k0 = 0; k0 < D_; k0++) {
        float a = attnrow[k0];
        v0 += a * cwo[(size_t)k0 * D_ + tid];
        v1 += a * cwo[(size_t)k0 * D_ + tid + 256];
    }
    float mean = block_sum(v0 + v1) * (1.f / 512.f);
    float d0 = v0 - mean, d1 = v1 - mean;
    float var = block_sum(d0 * d0 + d1 * d1) * (1.f / 512.f);
    float rs = rsqrtf(var + EPSV);
    x[(size_t)r * D_ + tid]       = d0 * rs * gam[tid] + bet[tid];
    x[(size_t)r * D_ + tid + 256] = d1 * rs * gam[tid + 256] + bet[tid + 256];
}

// ---------------------------------------------------------------------------
// x = LN(x + sum_parts (+ bias)) * g + b. One block per row.
// ---------------------------------------------------------------------------
__global__ __launch_bounds__(256) void ln_red_k(
    float* __restrict__ x, const float* __restrict__ parts, size_t pstride,
    int nparts, const float* __restrict__ bias,
    const float* __restrict__ gam, const float* __restrict__ bet)
{
    int r = blockIdx.x;
    float* xr = x + (size_t)r * D_;
    int tid = threadIdx.x;
    float v0 = xr[tid];
    float v1 = xr[tid + 256];
    for (int s = 0; s < nparts; s++) {
        const float* pr = parts + (size_t)s * pstride + (size_t)r * D_;
        v0 += pr[tid];
        v1 += pr[tid + 256];
    }
    if (bias) { v0 += bias[tid]; v1 += bias[tid + 256]; }
    float mean = block_sum(v0 + v1) * (1.f / 512.f);
    float d0 = v0 - mean, d1 = v1 - mean;
    float var = block_sum(d0 * d0 + d1 * d1) * (1.f / 512.f);
    float rs = rsqrtf(var + EPSV);
    xr[tid]       = d0 * rs * gam[tid] + bet[tid];
    xr[tid + 256] = d1 * rs * gam[tid + 256] + bet[tid + 256];
}

// ---------------------------------------------------------------------------
// logits: grid 125 x 256 thr = 64 cols x 4 K-chunks (in-block split-K).
// ---------------------------------------------------------------------------
__global__ __launch_bounds__(256) void logits_k(
    const float* __restrict__ x, const float* __restrict__ fcw,
    const float* __restrict__ fcb, float* __restrict__ logits, int t)
{
    __shared__ float xs[B_][D_];
    __shared__ float red[4][64][B_];
    int tid = threadIdx.x;
    for (int i = tid; i < B_ * D_; i += 256) {
        int b = i >> 9, d = i & 511;
        xs[b][d] = x[((size_t)t * B_ + b) * D_ + d];
    }
    __syncthreads();
    int lane = tid & 63, ks = tid >> 6;
    int col = blockIdx.x * 64 + lane;
    float acc[B_] = {};
    int kb = ks * 128;
    for (int k = kb; k < kb + 128; k++) {
        float w = fcw[(size_t)k * V_ + col];
        #pragma unroll
        for (int b = 0; b < B_; b++) acc[b] += xs[b][k] * w;
    }
    #pragma unroll
    for (int b = 0; b < B_; b++) red[ks][lane][b] = acc[b];
    __syncthreads();
    if (ks == 0) {
        float bias = fcb[col];
        #pragma unroll
        for (int b = 0; b < B_; b++) {
            float s = red[0][lane][b] + red[1][lane][b]
                    + red[2][lane][b] + red[3][lane][b];
            logits[(size_t)b * V_ + col] = s + bias;
        }
    }
}

// ---------------------------------------------------------------------------
__global__ __launch_bounds__(256) void argmax_k(
    const float* __restrict__ logits, int* __restrict__ tokens,
    int* __restrict__ done, int t)
{
    int b = blockIdx.x;
    const float* lr = logits + (size_t)b * V_;
    float bv = -1e30f; int bi = 0x7fffffff;
    for (int v = threadIdx.x; v < V_; v += 256) {
        float val = lr[v];
        if (val > bv) { bv = val; bi = v; }
    }
    __shared__ float sv[256];
    __shared__ int si[256];
    sv[threadIdx.x] = bv; si[threadIdx.x] = bi;
    __syncthreads();
    for (int s = 128; s; s >>= 1) {
        if (threadIdx.x < s) {
            float ov = sv[threadIdx.x + s]; int oi = si[threadIdx.x + s];
            if (ov > sv[threadIdx.x] ||
                (ov == sv[threadIdx.x] && oi < si[threadIdx.x])) {
                sv[threadIdx.x] = ov; si[threadIdx.x] = oi;
            }
        }
        __syncthreads();
    }
    if (threadIdx.x == 0) {
        int idx = si[0];
        int dn = done[b] | (idx == 2 ? 1 : 0);
        done[b] = dn;
        tokens[b * TP1 + t + 1] = dn ? 0 : idx;
    }
}

// ---------------------------------------------------------------------------
__global__ void writeout_k(const int* __restrict__ tokens, int* __restrict__ out)
{
    int i = threadIdx.x + blockIdx.x * 256;
    if (i < B_ * T_) {
        int b = i / T_, j = i % T_;
        out[i] = tokens[b * TP1 + j + 1];
    }
}

// ---------------------------------------------------------------------------
extern "C" void kernel_launch(void* const* d_in, const int* in_sizes, int n_in,
                              void* d_out, int out_size, void* d_ws, size_t ws_size,
                              hipStream_t stream)
{
    const float* enc   = (const float*)d_in[1];
    const float* pm    = (const float*)d_in[2];
    const float* embed = (const float*)d_in[3];
    const float* wq    = (const float*)d_in[4];
    const float* wk    = (const float*)d_in[5];
    const float* wv    = (const float*)d_in[6];
    const float* wo    = (const float*)d_in[7];
    const float* cwq   = (const float*)d_in[8];
    const float* cwk   = (const float*)d_in[9];
    const float* cwv   = (const float*)d_in[10];
    const float* cwo   = (const float*)d_in[11];
    const float* w1    = (const float*)d_in[12];
    const float* b1    = (const float*)d_in[13];
    const float* w2    = (const float*)d_in[14];
    const float* b2    = (const float*)d_in[15];
    const float* ln_g  = (const float*)d_in[16];
    const float* ln_b  = (const float*)d_in[17];
    const float* fcw   = (const float*)d_in[18];
    const float* fcb   = (const float*)d_in[19];

    float* ws = (float*)d_ws;
    size_t off = 0;
    float* x     = ws + off; off += XSZ;
    float* qkv   = ws + off; off += 3 * XSZ;      // q | kT | v
    float* parts = ws + off; off += 4 * XSZ;      // split-K partials
    float* ffnh  = ws + off; off += (size_t)TP1 * B_ * DFF_;
    float* logits= ws + off; off += (size_t)B_ * V_;
    float* KcT   = ws + off; off += (size_t)L_ * B_ * SENC * D_;
    float* Vc    = ws + off; off += (size_t)L_ * B_ * SENC * D_;
    float* cmask = ws + off; off += (size_t)B_ * SENC;
    int* tokens  = (int*)(ws + off); off += (B_ * TP1 + 63) & ~63;
    int* done    = (int*)(ws + off); off += 64;

    init_k<<<8, 256, 0, stream>>>(tokens, done, cmask, pm);

    // Precompute cross K (transposed) / V per layer
    const size_t KVL = (size_t)B_ * SENC * D_;
    for (int l = 0; l < L_; l++) {
        gemm32_k<<<dim3(8, (B_ * SENC) / 32), 128, 0, stream>>>(
            enc, cwk + (size_t)l * D_ * D_, nullptr, KcT + l * KVL,
            B_ * SENC, D_, D_, D_, 0, 0, 1);
        gemm32_k<<<dim3(8, (B_ * SENC) / 32), 128, 0, stream>>>(
            enc, cwv + (size_t)l * D_ * D_, nullptr, Vc + l * KVL,
            B_ * SENC, D_, D_, D_, 0, 0, 0);
    }

    for (int t = 0; t < T_; t++) {
        int P = t + 1;
        int M = P * B_;
        int mt = (M + 31) / 32;

        embed_k<<<dim3(P, B_), 256, 0, stream>>>(embed, tokens, x);

        for (int l = 0; l < L_; l++) {
            const size_t lw = (size_t)l * D_ * D_;
            // --- self attention block ---
            gemm_qkv_k<<<dim3(24, mt), 128, 0, stream>>>(
                x, wq + lw, wk + lw, wv + lw, qkv, M);
            self_fused_k<<<M, 256, 0, stream>>>(
                qkv, qkv + XSZ, qkv + 2 * XSZ, wo + lw, x,
                ln_g + (size_t)(l * 3 + 0) * D_, ln_b + (size_t)(l * 3 + 0) * D_, P);
            // --- cross attention block (fully row-local) ---
            cross_fused_k<<<M, 256, 0, stream>>>(
                KcT + l * KVL, Vc + l * KVL, cmask, cwq + lw, cwo + lw, x,
                ln_g + (size_t)(l * 3 + 1) * D_, ln_b + (size_t)(l * 3 + 1) * D_);
            // --- FFN ---
            gemm32_k<<<dim3(32, mt), 128, 0, stream>>>(
                x, w1 + (size_t)l * D_ * DFF_, b1 + (size_t)l * DFF_, ffnh,
                M, DFF_, D_, D_, 0, 1, 0);
            gemm32_k<<<dim3(8, mt, 4), 128, 0, stream>>>(
                ffnh, w2 + (size_t)l * DFF_ * D_, nullptr, parts,
                M, D_, DFF_, 512, XSZ, 0, 0);
            ln_red_k<<<M, 256, 0, stream>>>(x, parts, XSZ, 4, b2 + (size_t)l * D_,
                ln_g + (size_t)(l * 3 + 2) * D_, ln_b + (size_t)(l * 3 + 2) * D_);
        }

        logits_k<<<V_ / 64, 256, 0, stream>>>(x, fcw, fcb, logits, t);
        argmax_k<<<B_, 256, 0, stream>>>(logits, tokens, done, t);
    }

    writeout_k<<<2, 256, 0, stream>>>(tokens, (int*)d_out);
}

// Round 5
// 24316.591 us; speedup vs baseline: 3.7356x; 1.1150x over previous
//
#include <hip/hip_runtime.h>
#include <math.h>

#define L_   4
#define H_   8
#define D_   512
#define DH   64
#define DFF_ 2048
#define V_   8000
#define B_   16
#define SENC 128
#define T_   32
#define TP1  33
#define NEGV -1e9f
#define EPSV 1e-6f
#define SQRTD 22.627416997969522f   // sqrt(512)
#define XSZ  ((size_t)TP1 * B_ * D_)   // 270336 floats

// ---------------------------------------------------------------------------
// fp32 GEMM, 32x64 tile, 256 threads (2x4 micro-tile), double-buffered LDS,
// float4 global loads. k-range = [blockIdx.z*kchunk, +kchunk); block z
// writes C + z*pstride. tmode==1: KcT transpose epilogue.
// ---------------------------------------------------------------------------
__global__ __launch_bounds__(256) void gemm32_k(
    const float* __restrict__ A, const float* __restrict__ W,
    const float* __restrict__ bias, float* __restrict__ C,
    int M, int N, int K, int kchunk, size_t pstride, int relu, int tmode)
{
    __shared__ __align__(16) float As[2][16][34];
    __shared__ __align__(16) float Bs[2][16][68];
    int tid = threadIdx.x;
    int tx = tid & 15, ty = tid >> 4;          // tx: 4 cols, ty: 2 rows
    int m0 = blockIdx.y * 32, n0 = blockIdx.x * 64;
    int kbeg = blockIdx.z * kchunk;
    int niter = kchunk >> 4;
    C += (size_t)blockIdx.z * pstride;
    int am = tid >> 2, aseg = tid & 3;         // A loader (tid<128)
    int bk = tid >> 4, bc4 = (tid & 15) * 4;   // B loader (all 256)
    float4 aReg = make_float4(0.f, 0.f, 0.f, 0.f), bReg;
    {
        int k0 = kbeg;
        if (tid < 128) {
            int gm = m0 + am;
            if (gm < M) aReg = *(const float4*)&A[(size_t)gm * K + k0 + aseg * 4];
        }
        bReg = *(const float4*)&W[(size_t)(k0 + bk) * N + n0 + bc4];
    }
    if (tid < 128) {
        As[0][aseg * 4 + 0][am] = aReg.x;
        As[0][aseg * 4 + 1][am] = aReg.y;
        As[0][aseg * 4 + 2][am] = aReg.z;
        As[0][aseg * 4 + 3][am] = aReg.w;
    }
    *(float4*)&Bs[0][bk][bc4] = bReg;
    __syncthreads();
    float acc[2][4] = {};
    for (int it = 0; it < niter; it++) {
        int cur = it & 1;
        if (it + 1 < niter) {
            int k0 = kbeg + (it + 1) * 16;
            if (tid < 128) {
                int gm = m0 + am;
                aReg = make_float4(0.f, 0.f, 0.f, 0.f);
                if (gm < M) aReg = *(const float4*)&A[(size_t)gm * K + k0 + aseg * 4];
            }
            bReg = *(const float4*)&W[(size_t)(k0 + bk) * N + n0 + bc4];
        }
        #pragma unroll
        for (int kk = 0; kk < 16; kk++) {
            float2 a2 = *(const float2*)&As[cur][kk][ty * 2];
            float4 b4 = *(const float4*)&Bs[cur][kk][tx * 4];
            acc[0][0] += a2.x * b4.x; acc[0][1] += a2.x * b4.y;
            acc[0][2] += a2.x * b4.z; acc[0][3] += a2.x * b4.w;
            acc[1][0] += a2.y * b4.x; acc[1][1] += a2.y * b4.y;
            acc[1][2] += a2.y * b4.z; acc[1][3] += a2.y * b4.w;
        }
        if (it + 1 < niter) {
            int nxt = 1 - cur;
            if (tid < 128) {
                As[nxt][aseg * 4 + 0][am] = aReg.x;
                As[nxt][aseg * 4 + 1][am] = aReg.y;
                As[nxt][aseg * 4 + 2][am] = aReg.z;
                As[nxt][aseg * 4 + 3][am] = aReg.w;
            }
            *(float4*)&Bs[nxt][bk][bc4] = bReg;
        }
        __syncthreads();
    }
    #pragma unroll
    for (int i = 0; i < 2; i++) {
        int gm = m0 + ty * 2 + i;
        if (gm >= M) continue;
        #pragma unroll
        for (int j = 0; j < 4; j++) {
            int gn = n0 + tx * 4 + j;
            float vv = acc[i][j];
            if (bias) vv += bias[gn];
            if (relu) vv = fmaxf(vv, 0.f);
            if (tmode == 1)
                C[(size_t)(gm >> 7) * 65536 + (size_t)gn * SENC + (gm & 127)] = vv;
            else
                C[(size_t)gm * N + gn] = vv;
        }
    }
}

// ---------------------------------------------------------------------------
// Fused QKV: blockIdx.x: sel = x>>3 in {q,k,v}, n-tile = x&7. N=K=512.
// q,v row-major; k TRANSPOSED: kT[((b*8+h)*64+d)*33 + p], gm=p*16+b, gn=h*64+d.
// ---------------------------------------------------------------------------
__global__ __launch_bounds__(256) void gemm_qkv_k(
    const float* __restrict__ A, const float* __restrict__ W0,
    const float* __restrict__ W1, const float* __restrict__ W2,
    float* __restrict__ Cb, int M)
{
    __shared__ __align__(16) float As[2][16][34];
    __shared__ __align__(16) float Bs[2][16][68];
    int sel = blockIdx.x >> 3;
    const float* W = (sel == 0) ? W0 : ((sel == 1) ? W1 : W2);
    float* C = Cb + (size_t)sel * XSZ;
    int tid = threadIdx.x;
    int tx = tid & 15, ty = tid >> 4;
    int m0 = blockIdx.y * 32, n0 = (blockIdx.x & 7) * 64;
    int am = tid >> 2, aseg = tid & 3;
    int bk = tid >> 4, bc4 = (tid & 15) * 4;
    float4 aReg = make_float4(0.f, 0.f, 0.f, 0.f), bReg;
    {
        if (tid < 128) {
            int gm = m0 + am;
            if (gm < M) aReg = *(const float4*)&A[(size_t)gm * D_ + aseg * 4];
        }
        bReg = *(const float4*)&W[(size_t)bk * D_ + n0 + bc4];
    }
    if (tid < 128) {
        As[0][aseg * 4 + 0][am] = aReg.x;
        As[0][aseg * 4 + 1][am] = aReg.y;
        As[0][aseg * 4 + 2][am] = aReg.z;
        As[0][aseg * 4 + 3][am] = aReg.w;
    }
    *(float4*)&Bs[0][bk][bc4] = bReg;
    __syncthreads();
    float acc[2][4] = {};
    for (int it = 0; it < 32; it++) {
        int cur = it & 1;
        if (it + 1 < 32) {
            int k0 = (it + 1) * 16;
            if (tid < 128) {
                int gm = m0 + am;
                aReg = make_float4(0.f, 0.f, 0.f, 0.f);
                if (gm < M) aReg = *(const float4*)&A[(size_t)gm * D_ + k0 + aseg * 4];
            }
            bReg = *(const float4*)&W[(size_t)(k0 + bk) * D_ + n0 + bc4];
        }
        #pragma unroll
        for (int kk = 0; kk < 16; kk++) {
            float2 a2 = *(const float2*)&As[cur][kk][ty * 2];
            float4 b4 = *(const float4*)&Bs[cur][kk][tx * 4];
            acc[0][0] += a2.x * b4.x; acc[0][1] += a2.x * b4.y;
            acc[0][2] += a2.x * b4.z; acc[0][3] += a2.x * b4.w;
            acc[1][0] += a2.y * b4.x; acc[1][1] += a2.y * b4.y;
            acc[1][2] += a2.y * b4.z; acc[1][3] += a2.y * b4.w;
        }
        if (it + 1 < 32) {
            int nxt = 1 - cur;
            if (tid < 128) {
                As[nxt][aseg * 4 + 0][am] = aReg.x;
                As[nxt][aseg * 4 + 1][am] = aReg.y;
                As[nxt][aseg * 4 + 2][am] = aReg.z;
                As[nxt][aseg * 4 + 3][am] = aReg.w;
            }
            *(float4*)&Bs[nxt][bk][bc4] = bReg;
        }
        __syncthreads();
    }
    #pragma unroll
    for (int i = 0; i < 2; i++) {
        int gm = m0 + ty * 2 + i;
        if (gm >= M) continue;
        #pragma unroll
        for (int j = 0; j < 4; j++) {
            int gn = n0 + tx * 4 + j;
            if (sel == 1)
                C[(size_t)(gm & 15) * 16896 + (size_t)gn * TP1 + (gm >> 4)] =
                    acc[i][j];
            else
                C[(size_t)gm * D_ + gn] = acc[i][j];
        }
    }
}

// ---------------------------------------------------------------------------
__global__ void init_k(int* __restrict__ tokens, int* __restrict__ done,
                       float* __restrict__ cmask, const float* __restrict__ pm)
{
    int tid = threadIdx.x + blockIdx.x * 256;
    if (tid < B_ * TP1) tokens[tid] = ((tid % TP1) == 0) ? 1 : 0;
    if (tid < B_) done[tid] = 0;
    if (tid < B_ * SENC) cmask[tid] = pm[tid] * NEGV;
}

// ---------------------------------------------------------------------------
__global__ __launch_bounds__(256) void embed_k(
    const float* __restrict__ embed, const int* __restrict__ tokens,
    float* __restrict__ x)
{
    int p = blockIdx.x;
    int b = blockIdx.y;
    int tok = tokens[b * TP1 + p];
    const float* e = embed + (size_t)tok * D_;
    float* xr = x + ((size_t)p * B_ + b) * D_;
    for (int d = threadIdx.x; d < D_; d += 256) {
        float fd = (float)(2 * (d / 2)) / (float)D_;
        float ang = (float)p / powf(10000.f, fd);
        float pe = (d & 1) ? cosf(ang) : sinf(ang);
        xr[d] = e[d] * SQRTD + pe;
    }
}

// ---------------------------------------------------------------------------
__device__ __forceinline__ float block_sum(float s) {
    __shared__ float red[4];
    #pragma unroll
    for (int off = 32; off; off >>= 1) s += __shfl_xor(s, off);
    if ((threadIdx.x & 63) == 0) red[threadIdx.x >> 6] = s;
    __syncthreads();
    float tot = red[0] + red[1] + red[2] + red[3];
    __syncthreads();
    return tot;
}

// ---------------------------------------------------------------------------
// MEGA: self-attn + wo + LN + cross(q-proj, attn, cwo) + LN. Block per row.
// q row-major; kT [(b*8+h)*64+d][33]; v row-major; KcT [(b*8+h)*64+d][128];
// Vc row-major. lg/lb point at ln[l][0]; second LN uses +D_ offset.
// ---------------------------------------------------------------------------
__global__ __launch_bounds__(256) void attn_mega_k(
    const float* __restrict__ q, const float* __restrict__ kT,
    const float* __restrict__ v, const float* __restrict__ wo,
    const float* __restrict__ KcT, const float* __restrict__ Vc,
    const float* __restrict__ cmask, const float* __restrict__ cwq,
    const float* __restrict__ cwo, float* __restrict__ x,
    const float* __restrict__ lg, const float* __restrict__ lb, int P)
{
    int r = blockIdx.x, b = r & 15;
    int tid = threadIdx.x;
    int c0 = tid * 2;
    __shared__ float xs[D_], arow[D_];
    __shared__ float scs[H_][SENC];
    __shared__ float inv[H_];
    // ---- self scores: thread (h=tid>>5, kp=tid&31)
    {
        int kp = tid & 31, h = tid >> 5;
        float acc = 0.f;
        if (kp < P) {
            const float* qr = q + (size_t)r * D_ + h * 64;
            const float* kb = kT + ((size_t)(b * 8 + h) * 64) * TP1 + kp;
            #pragma unroll 8
            for (int d = 0; d < 64; d++) acc += qr[d] * kb[(size_t)d * TP1];
        }
        scs[h][kp] = acc * 0.125f;
    }
    __syncthreads();
    if (tid < 8) {
        float mx = -1e30f;
        for (int j = 0; j < P; j++) mx = fmaxf(mx, scs[tid][j]);
        float sum = 0.f;
        for (int j = 0; j < P; j++) {
            float e = expf(scs[tid][j] - mx);
            scs[tid][j] = e;
            sum += e;
        }
        inv[tid] = 1.f / sum;
    }
    __syncthreads();
    // ---- weighted V -> arow
    {
        int h = c0 >> 6;
        float o0 = 0.f, o1 = 0.f;
        for (int j = 0; j < P; j++) {
            float2 vv = *(const float2*)&v[((size_t)j * B_ + b) * D_ + c0];
            float w = scs[h][j];
            o0 += w * vv.x; o1 += w * vv.y;
        }
        arow[c0]     = o0 * inv[h];
        arow[c0 + 1] = o1 * inv[h];
    }
    __syncthreads();
    // ---- wo out-proj + residual + LN -> xs
    {
        float2 xv = *(const float2*)&x[(size_t)r * D_ + c0];
        float v0 = xv.x, v1 = xv.y;
        #pragma unroll 8
        for (int k = 0; k < D_; k++) {
            float a = arow[k];
            float2 wv = *(const float2*)&wo[(size_t)k * D_ + c0];
            v0 += a * wv.x; v1 += a * wv.y;
        }
        float mean = block_sum(v0 + v1) * (1.f / 512.f);
        float d0 = v0 - mean, d1 = v1 - mean;
        float var = block_sum(d0 * d0 + d1 * d1) * (1.f / 512.f);
        float rs = rsqrtf(var + EPSV);
        xs[c0]     = d0 * rs * lg[c0]     + lb[c0];
        xs[c0 + 1] = d1 * rs * lg[c0 + 1] + lb[c0 + 1];
    }
    __syncthreads();
    // ---- cross q-proj -> arow (reused as qrow)
    {
        float q0 = 0.f, q1 = 0.f;
        #pragma unroll 8
        for (int k = 0; k < D_; k++) {
            float a = xs[k];
            float2 wv = *(const float2*)&cwq[(size_t)k * D_ + c0];
            q0 += a * wv.x; q1 += a * wv.y;
        }
        arow[c0] = q0; arow[c0 + 1] = q1;
    }
    __syncthreads();
    // ---- cross scores: 4 (h,s) pairs per thread
    #pragma unroll
    for (int j = 0; j < 4; j++) {
        int idx = tid + j * 256;
        int h = idx >> 7, s = idx & 127;
        const float* kb = KcT + ((size_t)(b * 512 + h * 64)) * SENC + s;
        float acc = 0.f;
        #pragma unroll 8
        for (int d = 0; d < 64; d++) acc += arow[h * 64 + d] * kb[(size_t)d * SENC];
        scs[h][s] = acc * 0.125f + cmask[b * SENC + s];
    }
    __syncthreads();
    if (tid < 8) {
        float mx = -1e30f;
        for (int s = 0; s < SENC; s++) mx = fmaxf(mx, scs[tid][s]);
        float sum = 0.f;
        for (int s = 0; s < SENC; s++) {
            float e = expf(scs[tid][s] - mx);
            scs[tid][s] = e;
            sum += e;
        }
        inv[tid] = 1.f / sum;
    }
    __syncthreads();
    // ---- cross weighted V -> arow (qrow dead after score phase)
    {
        int h = c0 >> 6;
        float o0 = 0.f, o1 = 0.f;
        for (int s = 0; s < SENC; s++) {
            float2 vv = *(const float2*)&Vc[((size_t)b * SENC + s) * D_ + c0];
            float w = scs[h][s];
            o0 += w * vv.x; o1 += w * vv.y;
        }
        arow[c0]     = o0 * inv[h];
        arow[c0 + 1] = o1 * inv[h];
    }
    __syncthreads();
    // ---- cwo out-proj + residual(xs) + LN -> x
    {
        float v0 = xs[c0], v1 = xs[c0 + 1];
        #pragma unroll 8
        for (int k = 0; k < D_; k++) {
            float a = arow[k];
            float2 wv = *(const float2*)&cwo[(size_t)k * D_ + c0];
            v0 += a * wv.x; v1 += a * wv.y;
        }
        float mean = block_sum(v0 + v1) * (1.f / 512.f);
        float d0 = v0 - mean, d1 = v1 - mean;
        float var = block_sum(d0 * d0 + d1 * d1) * (1.f / 512.f);
        float rs = rsqrtf(var + EPSV);
        x[(size_t)r * D_ + c0]     = d0 * rs * lg[D_ + c0]     + lb[D_ + c0];
        x[(size_t)r * D_ + c0 + 1] = d1 * rs * lg[D_ + c0 + 1] + lb[D_ + c0 + 1];
    }
}

// ---------------------------------------------------------------------------
// x = LN(x + sum_parts (+ bias)) * g + b. One block per row.
// ---------------------------------------------------------------------------
__global__ __launch_bounds__(256) void ln_red_k(
    float* __restrict__ x, const float* __restrict__ parts, size_t pstride,
    int nparts, const float* __restrict__ bias,
    const float* __restrict__ gam, const float* __restrict__ bet)
{
    int r = blockIdx.x;
    float* xr = x + (size_t)r * D_;
    int tid = threadIdx.x;
    float v0 = xr[tid];
    float v1 = xr[tid + 256];
    for (int s = 0; s < nparts; s++) {
        const float* pr = parts + (size_t)s * pstride + (size_t)r * D_;
        v0 += pr[tid];
        v1 += pr[tid + 256];
    }
    if (bias) { v0 += bias[tid]; v1 += bias[tid + 256]; }
    float mean = block_sum(v0 + v1) * (1.f / 512.f);
    float d0 = v0 - mean, d1 = v1 - mean;
    float var = block_sum(d0 * d0 + d1 * d1) * (1.f / 512.f);
    float rs = rsqrtf(var + EPSV);
    xr[tid]       = d0 * rs * gam[tid] + bet[tid];
    xr[tid + 256] = d1 * rs * gam[tid + 256] + bet[tid + 256];
}

// ---------------------------------------------------------------------------
// logits -> per-block argmax candidates. Grid 125 x 256 thr = 64 cols x
// 4 K-chunks; wave 0 reduces its 64 cols per batch (val,idx).
// ---------------------------------------------------------------------------
__global__ __launch_bounds__(256) void logits_k(
    const float* __restrict__ x, const float* __restrict__ fcw,
    const float* __restrict__ fcb, float* __restrict__ cand_v,
    int* __restrict__ cand_i, int t)
{
    __shared__ float xs[B_][D_];
    __shared__ float red[4][64][B_];
    int tid = threadIdx.x;
    for (int i = tid; i < B_ * D_; i += 256) {
        int b = i >> 9, d = i & 511;
        xs[b][d] = x[((size_t)t * B_ + b) * D_ + d];
    }
    __syncthreads();
    int lane = tid & 63, ks = tid >> 6;
    int col = blockIdx.x * 64 + lane;
    float acc[B_] = {};
    int kb = ks * 128;
    for (int k = kb; k < kb + 128; k++) {
        float w = fcw[(size_t)k * V_ + col];
        #pragma unroll
        for (int b = 0; b < B_; b++) acc[b] += xs[b][k] * w;
    }
    #pragma unroll
    for (int b = 0; b < B_; b++) red[ks][lane][b] = acc[b];
    __syncthreads();
    if (ks == 0) {      // wave 0 only
        float bias = fcb[col];
        #pragma unroll
        for (int b = 0; b < B_; b++) {
            float val = red[0][lane][b] + red[1][lane][b]
                      + red[2][lane][b] + red[3][lane][b] + bias;
            int idx = col;
            #pragma unroll
            for (int off = 32; off; off >>= 1) {
                float ov = __shfl_down(val, off);
                int oi = __shfl_down(idx, off);
                if (ov > val || (ov == val && oi < idx)) { val = ov; idx = oi; }
            }
            if (lane == 0) {
                cand_v[(size_t)b * 125 + blockIdx.x] = val;
                cand_i[(size_t)b * 125 + blockIdx.x] = idx;
            }
        }
    }
}

// ---------------------------------------------------------------------------
// Reduce 125 candidates per batch; token update. One block per batch.
// ---------------------------------------------------------------------------
__global__ __launch_bounds__(128) void argmax_k(
    const float* __restrict__ cand_v, const int* __restrict__ cand_i,
    int* __restrict__ tokens, int* __restrict__ done, int t)
{
    int b = blockIdx.x;
    int tid = threadIdx.x;
    float val = -1e30f; int idx = 0x7fffffff;
    if (tid < 125) { val = cand_v[(size_t)b * 125 + tid]; idx = cand_i[(size_t)b * 125 + tid]; }
    __shared__ float sv[128];
    __shared__ int si[128];
    sv[tid] = val; si[tid] = idx;
    __syncthreads();
    for (int s = 64; s; s >>= 1) {
        if (tid < s) {
            float ov = sv[tid + s]; int oi = si[tid + s];
            if (ov > sv[tid] || (ov == sv[tid] && oi < si[tid])) {
                sv[tid] = ov; si[tid] = oi;
            }
        }
        __syncthreads();
    }
    if (tid == 0) {
        int best = si[0];
        int dn = done[b] | (best == 2 ? 1 : 0);
        done[b] = dn;
        tokens[b * TP1 + t + 1] = dn ? 0 : best;
    }
}

// ---------------------------------------------------------------------------
__global__ void writeout_k(const int* __restrict__ tokens, int* __restrict__ out)
{
    int i = threadIdx.x + blockIdx.x * 256;
    if (i < B_ * T_) {
        int b = i / T_, j = i % T_;
        out[i] = tokens[b * TP1 + j + 1];
    }
}

// ---------------------------------------------------------------------------
extern "C" void kernel_launch(void* const* d_in, const int* in_sizes, int n_in,
                              void* d_out, int out_size, void* d_ws, size_t ws_size,
                              hipStream_t stream)
{
    const float* enc   = (const float*)d_in[1];
    const float* pm    = (const float*)d_in[2];
    const float* embed = (const float*)d_in[3];
    const float* wq    = (const float*)d_in[4];
    const float* wk    = (const float*)d_in[5];
    const float* wv    = (const float*)d_in[6];
    const float* wo    = (const float*)d_in[7];
    const float* cwq   = (const float*)d_in[8];
    const float* cwk   = (const float*)d_in[9];
    const float* cwv   = (const float*)d_in[10];
    const float* cwo   = (const float*)d_in[11];
    const float* w1    = (const float*)d_in[12];
    const float* b1    = (const float*)d_in[13];
    const float* w2    = (const float*)d_in[14];
    const float* b2    = (const float*)d_in[15];
    const float* ln_g  = (const float*)d_in[16];
    const float* ln_b  = (const float*)d_in[17];
    const float* fcw   = (const float*)d_in[18];
    const float* fcb   = (const float*)d_in[19];

    float* ws = (float*)d_ws;
    size_t off = 0;
    float* x     = ws + off; off += XSZ;
    float* qkv   = ws + off; off += 3 * XSZ;      // q | kT | v
    float* parts = ws + off; off += 4 * XSZ;      // split-K partials
    float* ffnh  = ws + off; off += (size_t)TP1 * B_ * DFF_;
    float* cand_v= ws + off; off += (size_t)B_ * 125;
    float* KcT   = ws + off; off += (size_t)L_ * B_ * SENC * D_;
    float* Vc    = ws + off; off += (size_t)L_ * B_ * SENC * D_;
    float* cmask = ws + off; off += (size_t)B_ * SENC;
    int* cand_i  = (int*)(ws + off); off += (size_t)B_ * 125;
    int* tokens  = (int*)(ws + off); off += (B_ * TP1 + 63) & ~63;
    int* done    = (int*)(ws + off); off += 64;

    init_k<<<8, 256, 0, stream>>>(tokens, done, cmask, pm);

    // Precompute cross K (transposed) / V per layer
    const size_t KVL = (size_t)B_ * SENC * D_;
    for (int l = 0; l < L_; l++) {
        gemm32_k<<<dim3(8, (B_ * SENC) / 32), 256, 0, stream>>>(
            enc, cwk + (size_t)l * D_ * D_, nullptr, KcT + l * KVL,
            B_ * SENC, D_, D_, D_, 0, 0, 1);
        gemm32_k<<<dim3(8, (B_ * SENC) / 32), 256, 0, stream>>>(
            enc, cwv + (size_t)l * D_ * D_, nullptr, Vc + l * KVL,
            B_ * SENC, D_, D_, D_, 0, 0, 0);
    }

    for (int t = 0; t < T_; t++) {
        int P = t + 1;
        int M = P * B_;
        int mt = (M + 31) / 32;

        embed_k<<<dim3(P, B_), 256, 0, stream>>>(embed, tokens, x);

        for (int l = 0; l < L_; l++) {
            const size_t lw = (size_t)l * D_ * D_;
            gemm_qkv_k<<<dim3(24, mt), 256, 0, stream>>>(
                x, wq + lw, wk + lw, wv + lw, qkv, M);
            attn_mega_k<<<M, 256, 0, stream>>>(
                qkv, qkv + XSZ, qkv + 2 * XSZ, wo + lw,
                KcT + l * KVL, Vc + l * KVL, cmask, cwq + lw, cwo + lw, x,
                ln_g + (size_t)(l * 3 + 0) * D_, ln_b + (size_t)(l * 3 + 0) * D_, P);
            gemm32_k<<<dim3(32, mt), 256, 0, stream>>>(
                x, w1 + (size_t)l * D_ * DFF_, b1 + (size_t)l * DFF_, ffnh,
                M, DFF_, D_, D_, 0, 1, 0);
            gemm32_k<<<dim3(8, mt, 4), 256, 0, stream>>>(
                ffnh, w2 + (size_t)l * DFF_ * D_, nullptr, parts,
                M, D_, DFF_, 512, XSZ, 0, 0);
            ln_red_k<<<M, 256, 0, stream>>>(x, parts, XSZ, 4, b2 + (size_t)l * D_,
                ln_g + (size_t)(l * 3 + 2) * D_, ln_b + (size_t)(l * 3 + 2) * D_);
        }

        logits_k<<<V_ / 64, 256, 0, stream>>>(x, fcw, fcb, cand_v, cand_i, t);
        argmax_k<<<B_, 128, 0, stream>>>(cand_v, cand_i, tokens, done, t);
    }

    writeout_k<<<2, 256, 0, stream>>>(tokens, (int*)d_out);
}